// Round 3
// baseline (167.491 us; speedup 1.0000x reference)
//
#include <hip/hip_runtime.h>

#define NKC 256   // clusters (K)
#define ND  64    // feature dim (D)

using v8bf = __attribute__((ext_vector_type(8))) __bf16;
using v4f  = __attribute__((ext_vector_type(4))) float;
using v4u  = __attribute__((ext_vector_type(4))) unsigned int;

__device__ __forceinline__ unsigned short f2bf(float f) {
    // round-to-nearest-even f32 -> bf16 (inputs are finite normals; no NaN path)
    unsigned int x = __float_as_uint(f);
    x += 0x7FFFu + ((x >> 16) & 1u);
    return (unsigned short)(x >> 16);
}

// Convert clusters (256x64 f32) to bf16 + per-row sum of squares, into workspace.
__global__ void prep_kernel(const float* __restrict__ clusters,
                            unsigned short* __restrict__ cbf,
                            float* __restrict__ csq) {
    int t = threadIdx.x;
    int lane = t & 63;
    int row = blockIdx.x * 4 + (t >> 6);
    float v = clusters[row * ND + lane];
    cbf[row * ND + lane] = f2bf(v);
    float p = v * v;
#pragma unroll
    for (int m = 1; m <= 32; m <<= 1) p += __shfl_xor(p, m);
    if (lane == 0) csq[row] = p;
}

// Hybrid: clusters in LDS (32KB, XOR-swizzled, staged ONCE per persistent
// block -> one barrier total), x streamed global->reg->bf16, zero barriers
// in the tile loop. 33KB LDS + <=128 VGPR -> 4 blocks/CU = 16 waves/CU.
__global__ __launch_bounds__(256, 4)
void cluster_kernel(const float* __restrict__ x,
                    const unsigned short* __restrict__ cbf,
                    const float* __restrict__ csq,
                    float* __restrict__ out,
                    int ntiles) {
    __shared__ __align__(16) unsigned short sc[NKC * ND];   // 32 KB
    __shared__ float scsq[NKC];

    const int t = threadIdx.x;

    // ---- stage clusters (256x64 bf16 = 32KB) swizzled; once per block
    {
        char* dst = (char*)sc;
        const char* src = (const char*)cbf;
#pragma unroll
        for (int i = 0; i < 8; ++i) {
            int byte = (t + i * 256) << 4;     // coalesced 16B chunks
            int crow = byte >> 7;              // /128 = cluster row
            v4u val = *(const v4u*)(src + byte);
            *(v4u*)(dst + (byte ^ ((crow & 7) << 4))) = val;
        }
        scsq[t] = csq[t];
    }
    __syncthreads();   // the only barrier in the kernel

    const int lane = t & 63;
    const int wid  = t >> 6;        // wave in block (0..3)
    const int lr   = lane & 15;
    const int hi   = lane >> 4;     // 0..3
    const int kg   = hi << 3;       // k-offset within 32: 0,8,16,24

    for (int tile = blockIdx.x; tile < ntiles; tile += gridDim.x) {
        const int row0 = tile * 64 + wid * 16;      // wave's first row
        // ---- A: lane loads row (row0+lr), k = kg+{0..7} and 32+kg+{0..7}
        const float* xp = x + (size_t)(row0 + lr) * ND + kg;
        v4f x00 = *(const v4f*)(xp);
        v4f x01 = *(const v4f*)(xp + 4);
        v4f x10 = *(const v4f*)(xp + 32);
        v4f x11 = *(const v4f*)(xp + 36);

        float v0[8], v1[8];
        *(v4f*)&v0[0] = x00; *(v4f*)&v0[4] = x01;
        *(v4f*)&v1[0] = x10; *(v4f*)&v1[4] = x11;

        // partial sumsq of this lane's 16 elems of row (row0+lr)
        float p = 0.f;
#pragma unroll
        for (int i = 0; i < 8; ++i) p += v0[i] * v0[i] + v1[i] * v1[i];
        // full row sumsq: reduce across the 4 hi-groups holding the same lr
        p += __shfl_xor(p, 16);
        p += __shfl_xor(p, 32);

        v4u u0, u1;
#pragma unroll
        for (int i = 0; i < 4; ++i) {
            u0[i] = (unsigned)f2bf(v0[2 * i]) | ((unsigned)f2bf(v0[2 * i + 1]) << 16);
            u1[i] = (unsigned)f2bf(v1[2 * i]) | ((unsigned)f2bf(v1[2 * i + 1]) << 16);
        }
        v8bf a0 = *(v8bf*)&u0;
        v8bf a1 = *(v8bf*)&u1;

        // ---- MFMA: 16 col-tiles x (K=64 as 2 steps), B from swizzled LDS
        v4f acc[16];
#pragma unroll
        for (int j = 0; j < 16; ++j) {
            const int brow = (j << 4) + lr;           // cluster index (col)
            const int bswz = (brow & 7) << 4;
            v8bf b0 = *(v8bf*)((char*)sc + ((brow * 128      + kg * 2) ^ bswz));
            v8bf b1 = *(v8bf*)((char*)sc + ((brow * 128 + 64 + kg * 2) ^ bswz));
            v4f c = {0.f, 0.f, 0.f, 0.f};
            c = __builtin_amdgcn_mfma_f32_16x16x32_bf16(a0, b0, c, 0, 0, 0);
            c = __builtin_amdgcn_mfma_f32_16x16x32_bf16(a1, b1, c, 0, 0, 0);
            acc[j] = c;
        }

        // ---- epilogue. C/D layout: col = lane&15 (cluster j*16+lr),
        // row = (lane>>4)*4 + reg  -> global row = row0 + hi*4 + r
        float xs[4];
#pragma unroll
        for (int r = 0; r < 4; ++r) xs[r] = __shfl(p, (hi << 2) + r);

        float ps[4] = {0.f, 0.f, 0.f, 0.f};
#pragma unroll
        for (int j = 0; j < 16; ++j) {
            const float cs = scsq[(j << 4) + lr];
#pragma unroll
            for (int r = 0; r < 4; ++r) {
                float d = xs[r] + cs - 2.0f * acc[j][r];
                float u = __builtin_amdgcn_rcpf(1.0f + d);
                acc[j][r] = u;
                ps[r] += u;
            }
        }
#pragma unroll
        for (int m = 1; m <= 8; m <<= 1) {
#pragma unroll
            for (int r = 0; r < 4; ++r) ps[r] += __shfl_xor(ps[r], m);
        }
        float inv[4];
#pragma unroll
        for (int r = 0; r < 4; ++r) inv[r] = __builtin_amdgcn_rcpf(ps[r]);

        float* orow = out + (size_t)(row0 + (hi << 2)) * NKC + lr;
#pragma unroll
        for (int r = 0; r < 4; ++r) {
#pragma unroll
            for (int j = 0; j < 16; ++j) {
                orow[(size_t)r * NKC + (j << 4)] = acc[j][r] * inv[r];
            }
        }
    }
}

extern "C" void kernel_launch(void* const* d_in, const int* in_sizes, int n_in,
                              void* d_out, int out_size, void* d_ws, size_t ws_size,
                              hipStream_t stream) {
    const float* x        = (const float*)d_in[0];
    const float* clusters = (const float*)d_in[1];
    float* out = (float*)d_out;
    const int N = in_sizes[0] / ND;                 // 262144
    const int ntiles = N / 64;                      // 4096

    unsigned short* cbf = (unsigned short*)d_ws;                         // 32 KB
    float* csq = (float*)((char*)d_ws + (size_t)NKC * ND * sizeof(unsigned short));

    prep_kernel<<<NKC / 4, 256, 0, stream>>>(clusters, cbf, csq);
    cluster_kernel<<<1024, 256, 0, stream>>>(x, cbf, csq, out, ntiles);
}

// Round 4
// 77.895 us; speedup vs baseline: 2.1502x; 2.1502x over previous
//
#include <hip/hip_runtime.h>

#define NKC 256   // clusters (K)
#define ND  64    // feature dim (D)

using v8bf = __attribute__((ext_vector_type(8))) __bf16;
using v4f  = __attribute__((ext_vector_type(4))) float;
using v4u  = __attribute__((ext_vector_type(4))) unsigned int;

__device__ __forceinline__ unsigned short f2bf(float f) {
    // round-to-nearest-even f32 -> bf16 (inputs are finite normals; no NaN path)
    unsigned int x = __float_as_uint(f);
    x += 0x7FFFu + ((x >> 16) & 1u);
    return (unsigned short)(x >> 16);
}

// Convert clusters (256x64 f32) to bf16 + per-row sum of squares, into workspace.
__global__ void prep_kernel(const float* __restrict__ clusters,
                            unsigned short* __restrict__ cbf,
                            float* __restrict__ csq) {
    int t = threadIdx.x;
    int lane = t & 63;
    int row = blockIdx.x * 4 + (t >> 6);
    float v = clusters[row * ND + lane];
    cbf[row * ND + lane] = f2bf(v);
    float p = v * v;
#pragma unroll
    for (int m = 1; m <= 32; m <<= 1) p += __shfl_xor(p, m);
    if (lane == 0) csq[row] = p;
}

// Swapped-operand MFMA: D[row=cluster, col=x-row]. Each lane owns ONE x-row;
// acc[j] = 4 consecutive cluster cols -> dwordx4 coalesced stores, scalar ps,
// no xs broadcast. Clusters in LDS (32KB swizzled, staged once per block).
__global__ __launch_bounds__(256, 4)
void cluster_kernel(const float* __restrict__ x,
                    const unsigned short* __restrict__ cbf,
                    const float* __restrict__ csq,
                    float* __restrict__ out) {
    __shared__ __align__(16) unsigned short sc[NKC * ND];   // 32 KB
    __shared__ float scsq[NKC];

    const int t = threadIdx.x;

    // ---- stage clusters (256x64 bf16 = 32KB) swizzled; once per block
    {
        char* dst = (char*)sc;
        const char* src = (const char*)cbf;
#pragma unroll
        for (int i = 0; i < 8; ++i) {
            int byte = (t + i * 256) << 4;     // coalesced 16B chunks
            int crow = byte >> 7;              // /128 = cluster row
            v4u val = *(const v4u*)(src + byte);
            *(v4u*)(dst + (byte ^ ((crow & 7) << 4))) = val;
        }
        scsq[t] = csq[t];
    }
    __syncthreads();   // the only barrier

    const int lane = t & 63;
    const int wid  = t >> 6;        // wave in block (0..3)
    const int lr   = lane & 15;
    const int hi   = lane >> 4;     // 0..3
    const int kg   = hi << 3;       // k-offset within 32: 0,8,16,24

    // ---- this lane's x-row; load k = kg+{0..7} and 32+kg+{0..7}
    const int row = blockIdx.x * 64 + wid * 16 + lr;
    const float* xp = x + (size_t)row * ND + kg;
    v4f x00 = *(const v4f*)(xp);
    v4f x01 = *(const v4f*)(xp + 4);
    v4f x10 = *(const v4f*)(xp + 32);
    v4f x11 = *(const v4f*)(xp + 36);

    float v0[8], v1[8];
    *(v4f*)&v0[0] = x00; *(v4f*)&v0[4] = x01;
    *(v4f*)&v1[0] = x10; *(v4f*)&v1[4] = x11;

    // full sumsq of this lane's x-row: partial (16 elems) + reduce over hi-groups
    float p = 0.f;
#pragma unroll
    for (int i = 0; i < 8; ++i) p += v0[i] * v0[i] + v1[i] * v1[i];
    p += __shfl_xor(p, 16);
    p += __shfl_xor(p, 32);

    v4u u0, u1;
#pragma unroll
    for (int i = 0; i < 4; ++i) {
        u0[i] = (unsigned)f2bf(v0[2 * i]) | ((unsigned)f2bf(v0[2 * i + 1]) << 16);
        u1[i] = (unsigned)f2bf(v1[2 * i]) | ((unsigned)f2bf(v1[2 * i + 1]) << 16);
    }
    v8bf a0 = *(v8bf*)&u0;   // x fragment (B operand), k 0..31
    v8bf a1 = *(v8bf*)&u1;   // x fragment, k 32..63

    // ---- MFMA: 16 cluster-tiles x (K=64 as 2 steps). A = clusters from LDS.
    v4f acc[16];
#pragma unroll
    for (int j = 0; j < 16; ++j) {
        const int brow = (j << 4) + lr;           // cluster row within tile
        const int bswz = (brow & 7) << 4;
        v8bf c0 = *(v8bf*)((char*)sc + ((brow * 128      + kg * 2) ^ bswz));
        v8bf c1 = *(v8bf*)((char*)sc + ((brow * 128 + 64 + kg * 2) ^ bswz));
        v4f c = {0.f, 0.f, 0.f, 0.f};
        c = __builtin_amdgcn_mfma_f32_16x16x32_bf16(c0, a0, c, 0, 0, 0);
        c = __builtin_amdgcn_mfma_f32_16x16x32_bf16(c1, a1, c, 0, 0, 0);
        acc[j] = c;   // D[row=cluster 16j+4hi+r, col=x-row lr] per lane
    }

    // ---- epilogue: u = 1/(1+d); ps = this lane's partial sum over its 64 clusters
    float ps = 0.f;
#pragma unroll
    for (int j = 0; j < 16; ++j) {
        v4f cs = *(const v4f*)&scsq[(j << 4) + (hi << 2)];
#pragma unroll
        for (int r = 0; r < 4; ++r) {
            float d = p + cs[r] - 2.0f * acc[j][r];
            float u = __builtin_amdgcn_rcpf(1.0f + d);
            acc[j][r] = u;
            ps += u;
        }
    }
    // full row sum: reduce over the 4 hi-groups holding the same x-row
    ps += __shfl_xor(ps, 16);
    ps += __shfl_xor(ps, 32);
    const float inv = __builtin_amdgcn_rcpf(ps);

    // ---- stores: dwordx4 per lane; wave covers 16 rows x 64B contiguous per j
    float* orow = out + (size_t)row * NKC + (hi << 2);
#pragma unroll
    for (int j = 0; j < 16; ++j) {
        v4f w;
#pragma unroll
        for (int r = 0; r < 4; ++r) w[r] = acc[j][r] * inv;
        *(v4f*)(orow + (j << 4)) = w;
    }
}

extern "C" void kernel_launch(void* const* d_in, const int* in_sizes, int n_in,
                              void* d_out, int out_size, void* d_ws, size_t ws_size,
                              hipStream_t stream) {
    const float* x        = (const float*)d_in[0];
    const float* clusters = (const float*)d_in[1];
    float* out = (float*)d_out;
    const int N = in_sizes[0] / ND;                 // 262144

    unsigned short* cbf = (unsigned short*)d_ws;                         // 32 KB
    float* csq = (float*)((char*)d_ws + (size_t)NKC * ND * sizeof(unsigned short));

    prep_kernel<<<NKC / 4, 256, 0, stream>>>(clusters, cbf, csq);
    cluster_kernel<<<N / 64, 256, 0, stream>>>(x, cbf, csq, out);
}

// Round 5
// 72.222 us; speedup vs baseline: 2.3191x; 1.0785x over previous
//
#include <hip/hip_runtime.h>

#define NKC 256   // clusters (K)
#define ND  64    // feature dim (D)

using v8bf = __attribute__((ext_vector_type(8))) __bf16;
using v4f  = __attribute__((ext_vector_type(4))) float;
using v4u  = __attribute__((ext_vector_type(4))) unsigned int;

__device__ __forceinline__ unsigned short f2bf(float f) {
    // round-to-nearest-even f32 -> bf16 (inputs are finite normals; no NaN path)
    unsigned int x = __float_as_uint(f);
    x += 0x7FFFu + ((x >> 16) & 1u);
    return (unsigned short)(x >> 16);
}

// Convert clusters (256x64 f32) to bf16 + per-row sum of squares, into workspace.
__global__ void prep_kernel(const float* __restrict__ clusters,
                            unsigned short* __restrict__ cbf,
                            float* __restrict__ csq) {
    int t = threadIdx.x;
    int lane = t & 63;
    int row = blockIdx.x * 4 + (t >> 6);
    float v = clusters[row * ND + lane];
    cbf[row * ND + lane] = f2bf(v);
    float p = v * v;
#pragma unroll
    for (int m = 1; m <= 32; m <<= 1) p += __shfl_xor(p, m);
    if (lane == 0) csq[row] = p;
}

// Swapped-operand MFMA (D[row=cluster, col=x-row]); clusters in LDS (32KB,
// swizzled, staged once). NEW in R5: after compute, reuse the cluster LDS as
// per-wave transpose scratch so every global store writes a FULL contiguous
// 1KB output row per wave-instruction (fill-kernel pattern, FETCH~0) instead
// of 64B half-lines (which triggered ~185MB of L2 write-allocate RMW fetch).
__global__ __launch_bounds__(256, 4)
void cluster_kernel(const float* __restrict__ x,
                    const unsigned short* __restrict__ cbf,
                    const float* __restrict__ csq,
                    float* __restrict__ out) {
    __shared__ __align__(16) unsigned short sc[NKC * ND];   // 32 KB
    __shared__ float scsq[NKC];

    const int t = threadIdx.x;

    // ---- stage clusters (256x64 bf16 = 32KB) swizzled; once per block
    {
        char* dst = (char*)sc;
        const char* src = (const char*)cbf;
#pragma unroll
        for (int i = 0; i < 8; ++i) {
            int byte = (t + i * 256) << 4;     // coalesced 16B chunks
            int crow = byte >> 7;              // /128 = cluster row
            v4u val = *(const v4u*)(src + byte);
            *(v4u*)(dst + (byte ^ ((crow & 7) << 4))) = val;
        }
        scsq[t] = csq[t];
    }
    __syncthreads();

    const int lane = t & 63;
    const int wid  = t >> 6;        // wave in block (0..3)
    const int lr   = lane & 15;
    const int hi   = lane >> 4;     // 0..3
    const int kg   = hi << 3;       // k-offset within 32: 0,8,16,24

    // ---- this lane's x-row; load k = kg+{0..7} and 32+kg+{0..7}
    const int row = blockIdx.x * 64 + wid * 16 + lr;
    const float* xp = x + (size_t)row * ND + kg;
    v4f x00 = *(const v4f*)(xp);
    v4f x01 = *(const v4f*)(xp + 4);
    v4f x10 = *(const v4f*)(xp + 32);
    v4f x11 = *(const v4f*)(xp + 36);

    float v0[8], v1[8];
    *(v4f*)&v0[0] = x00; *(v4f*)&v0[4] = x01;
    *(v4f*)&v1[0] = x10; *(v4f*)&v1[4] = x11;

    // full sumsq of this lane's x-row: partial (16 elems) + reduce over hi-groups
    float p = 0.f;
#pragma unroll
    for (int i = 0; i < 8; ++i) p += v0[i] * v0[i] + v1[i] * v1[i];
    p += __shfl_xor(p, 16);
    p += __shfl_xor(p, 32);

    v4u u0, u1;
#pragma unroll
    for (int i = 0; i < 4; ++i) {
        u0[i] = (unsigned)f2bf(v0[2 * i]) | ((unsigned)f2bf(v0[2 * i + 1]) << 16);
        u1[i] = (unsigned)f2bf(v1[2 * i]) | ((unsigned)f2bf(v1[2 * i + 1]) << 16);
    }
    v8bf a0 = *(v8bf*)&u0;   // x fragment (B operand), k 0..31
    v8bf a1 = *(v8bf*)&u1;   // x fragment, k 32..63

    // ---- MFMA: 16 cluster-tiles x (K=64 as 2 steps). A = clusters from LDS.
    v4f acc[16];
#pragma unroll
    for (int j = 0; j < 16; ++j) {
        const int brow = (j << 4) + lr;           // cluster row within tile
        const int bswz = (brow & 7) << 4;
        v8bf c0 = *(v8bf*)((char*)sc + ((brow * 128      + kg * 2) ^ bswz));
        v8bf c1 = *(v8bf*)((char*)sc + ((brow * 128 + 64 + kg * 2) ^ bswz));
        v4f c = {0.f, 0.f, 0.f, 0.f};
        c = __builtin_amdgcn_mfma_f32_16x16x32_bf16(c0, a0, c, 0, 0, 0);
        c = __builtin_amdgcn_mfma_f32_16x16x32_bf16(c1, a1, c, 0, 0, 0);
        acc[j] = c;   // D[row=cluster 16j+4hi+r, col=x-row lr] per lane
    }

    // ---- epilogue: u = 1/(1+d); normalize fully in registers
    float ps = 0.f;
#pragma unroll
    for (int j = 0; j < 16; ++j) {
        v4f cs = *(const v4f*)&scsq[(j << 4) + (hi << 2)];
#pragma unroll
        for (int r = 0; r < 4; ++r) {
            float d = p + cs[r] - 2.0f * acc[j][r];
            float u = __builtin_amdgcn_rcpf(1.0f + d);
            acc[j][r] = u;
            ps += u;
        }
    }
    ps += __shfl_xor(ps, 16);
    ps += __shfl_xor(ps, 32);
    const float inv = __builtin_amdgcn_rcpf(ps);
#pragma unroll
    for (int j = 0; j < 16; ++j) {
#pragma unroll
        for (int r = 0; r < 4; ++r) acc[j][r] *= inv;
    }

    // ---- all waves done reading sc -> reuse it as transpose scratch
    __syncthreads();

    // Per-wave 8KB slice; 2 rounds x 8 rows. Write swizzled, read back so
    // lane i holds cols [4i,4i+4) of one row -> 1KB contiguous per store.
    char* slice = (char*)sc + wid * 8192;
    const int q = lr & 7;                 // row-local within round
    const int rowbase = blockIdx.x * 64 + wid * 16;
#pragma unroll
    for (int rnd = 0; rnd < 2; ++rnd) {
        if ((lr >> 3) == rnd) {
#pragma unroll
            for (int j = 0; j < 16; ++j) {
                *(v4u*)(slice + q * 1024 + (((j << 6) + (hi << 4)) ^ (q << 4))) =
                    *(v4u*)&acc[j];
            }
        }
        __asm__ volatile("s_waitcnt lgkmcnt(0)" ::: "memory");
#pragma unroll
        for (int q2 = 0; q2 < 8; ++q2) {
            v4u val = *(v4u*)(slice + q2 * 1024 + ((lane << 4) ^ (q2 << 4)));
            float* orow = out + (size_t)(rowbase + rnd * 8 + q2) * NKC;
            *(v4u*)(orow + (lane << 2)) = val;
        }
        __asm__ volatile("s_waitcnt lgkmcnt(0)" ::: "memory");
    }
}

extern "C" void kernel_launch(void* const* d_in, const int* in_sizes, int n_in,
                              void* d_out, int out_size, void* d_ws, size_t ws_size,
                              hipStream_t stream) {
    const float* x        = (const float*)d_in[0];
    const float* clusters = (const float*)d_in[1];
    float* out = (float*)d_out;
    const int N = in_sizes[0] / ND;                 // 262144

    unsigned short* cbf = (unsigned short*)d_ws;                         // 32 KB
    float* csq = (float*)((char*)d_ws + (size_t)NKC * ND * sizeof(unsigned short));

    prep_kernel<<<NKC / 4, 256, 0, stream>>>(clusters, cbf, csq);
    cluster_kernel<<<N / 64, 256, 0, stream>>>(x, cbf, csq, out);
}

// Round 6
// 62.014 us; speedup vs baseline: 2.7009x; 1.1646x over previous
//
#include <hip/hip_runtime.h>

#define NKC 256   // clusters (K)
#define ND  64    // feature dim (D)

using v8bf = __attribute__((ext_vector_type(8))) __bf16;
using v4f  = __attribute__((ext_vector_type(4))) float;
using v4u  = __attribute__((ext_vector_type(4))) unsigned int;

__device__ __forceinline__ unsigned short f2bf(float f) {
    // round-to-nearest-even f32 -> bf16 (inputs are finite normals; no NaN path)
    unsigned int x = __float_as_uint(f);
    x += 0x7FFFu + ((x >> 16) & 1u);
    return (unsigned short)(x >> 16);
}

// Single fused kernel. Each block:
//  - converts clusters f32->bf16 into swizzled LDS itself (L2-hot, no prep
//    kernel, no d_ws round-trip, no inter-kernel drain)
//  - x global loads issued BEFORE staging so the barrier's vmcnt(0) overlaps
//    their HBM latency with staging VALU work
//  - swapped-operand MFMA (D[row=cluster, col=x-row])
//  - LDS transpose epilogue -> full 1KB-contiguous nontemporal row stores
__global__ __launch_bounds__(256, 4)
void cluster_kernel(const float* __restrict__ x,
                    const float* __restrict__ clusters,
                    float* __restrict__ out) {
    __shared__ __align__(16) unsigned short sc[NKC * ND];   // 32 KB
    __shared__ float scsq[NKC];

    const int t    = threadIdx.x;
    const int lane = t & 63;
    const int wid  = t >> 6;        // wave in block (0..3)
    const int lr   = lane & 15;
    const int hi   = lane >> 4;     // 0..3
    const int kg   = hi << 3;       // k-offset within 32: 0,8,16,24

    // ---- issue this lane's x-row loads FIRST (HBM latency hides under staging)
    const int row = blockIdx.x * 64 + wid * 16 + lr;
    const float* xp = x + (size_t)row * ND + kg;
    v4f x00 = *(const v4f*)(xp);
    v4f x01 = *(const v4f*)(xp + 4);
    v4f x10 = *(const v4f*)(xp + 32);
    v4f x11 = *(const v4f*)(xp + 36);

    // ---- stage clusters: f32 -> bf16 swizzled LDS + per-row sumsq.
    // 4 iters; thread handles 16 floats (64B, coalesced) of cluster row
    // (it*64 + t/4), segment (t&3).
    {
        const int seg  = t & 3;
        const int rloc = t >> 2;
#pragma unroll
        for (int it = 0; it < 4; ++it) {
            const int crow = it * 64 + rloc;
            const float* cp = clusters + crow * ND + seg * 16;
            v4f c0 = *(const v4f*)(cp);
            v4f c1 = *(const v4f*)(cp + 4);
            v4f c2 = *(const v4f*)(cp + 8);
            v4f c3 = *(const v4f*)(cp + 12);
            float cv[16];
            *(v4f*)&cv[0] = c0; *(v4f*)&cv[4] = c1;
            *(v4f*)&cv[8] = c2; *(v4f*)&cv[12] = c3;
            float ss = 0.f;
#pragma unroll
            for (int i = 0; i < 16; ++i) ss += cv[i] * cv[i];
            ss += __shfl_xor(ss, 1);
            ss += __shfl_xor(ss, 2);
            if (seg == 0) scsq[crow] = ss;
            v4u w0, w1;
#pragma unroll
            for (int i = 0; i < 4; ++i) {
                w0[i] = (unsigned)f2bf(cv[2*i])   | ((unsigned)f2bf(cv[2*i+1]) << 16);
                w1[i] = (unsigned)f2bf(cv[8+2*i]) | ((unsigned)f2bf(cv[9+2*i]) << 16);
            }
            const int swz = (crow & 7) << 4;
            const int byte0 = crow * 128 + seg * 32;
            *(v4u*)((char*)sc + ( byte0       ^ swz)) = w0;
            *(v4u*)((char*)sc + ((byte0 + 16) ^ swz)) = w1;
        }
    }
    __syncthreads();

    // ---- convert x, full-row sumsq
    float v0[8], v1[8];
    *(v4f*)&v0[0] = x00; *(v4f*)&v0[4] = x01;
    *(v4f*)&v1[0] = x10; *(v4f*)&v1[4] = x11;

    float p = 0.f;
#pragma unroll
    for (int i = 0; i < 8; ++i) p += v0[i] * v0[i] + v1[i] * v1[i];
    p += __shfl_xor(p, 16);
    p += __shfl_xor(p, 32);

    v4u u0, u1;
#pragma unroll
    for (int i = 0; i < 4; ++i) {
        u0[i] = (unsigned)f2bf(v0[2 * i]) | ((unsigned)f2bf(v0[2 * i + 1]) << 16);
        u1[i] = (unsigned)f2bf(v1[2 * i]) | ((unsigned)f2bf(v1[2 * i + 1]) << 16);
    }
    v8bf a0 = *(v8bf*)&u0;   // x fragment (B operand), k 0..31
    v8bf a1 = *(v8bf*)&u1;   // x fragment, k 32..63

    // ---- MFMA: 16 cluster-tiles x (K=64 as 2 steps). A = clusters from LDS.
    v4f acc[16];
#pragma unroll
    for (int j = 0; j < 16; ++j) {
        const int brow = (j << 4) + lr;           // cluster row within tile
        const int bswz = (brow & 7) << 4;
        v8bf c0 = *(v8bf*)((char*)sc + ((brow * 128      + kg * 2) ^ bswz));
        v8bf c1 = *(v8bf*)((char*)sc + ((brow * 128 + 64 + kg * 2) ^ bswz));
        v4f c = {0.f, 0.f, 0.f, 0.f};
        c = __builtin_amdgcn_mfma_f32_16x16x32_bf16(c0, a0, c, 0, 0, 0);
        c = __builtin_amdgcn_mfma_f32_16x16x32_bf16(c1, a1, c, 0, 0, 0);
        acc[j] = c;   // D[row=cluster 16j+4hi+r, col=x-row lr] per lane
    }

    // ---- epilogue: u = 1/(1+d); normalize fully in registers
    float ps = 0.f;
#pragma unroll
    for (int j = 0; j < 16; ++j) {
        v4f cs = *(const v4f*)&scsq[(j << 4) + (hi << 2)];
#pragma unroll
        for (int r = 0; r < 4; ++r) {
            float d = p + cs[r] - 2.0f * acc[j][r];
            float u = __builtin_amdgcn_rcpf(1.0f + d);
            acc[j][r] = u;
            ps += u;
        }
    }
    ps += __shfl_xor(ps, 16);
    ps += __shfl_xor(ps, 32);
    const float inv = __builtin_amdgcn_rcpf(ps);
#pragma unroll
    for (int j = 0; j < 16; ++j) {
#pragma unroll
        for (int r = 0; r < 4; ++r) acc[j][r] *= inv;
    }

    // ---- all waves done reading sc -> reuse it as transpose scratch
    __syncthreads();

    // Per-wave 8KB slice; 2 rounds x 8 rows. Write swizzled, read back so
    // lane i holds cols [4i,4i+4) of one row -> 1KB contiguous nt store.
    char* slice = (char*)sc + wid * 8192;
    const int q = lr & 7;                 // row-local within round
    const int rowbase = blockIdx.x * 64 + wid * 16;
#pragma unroll
    for (int rnd = 0; rnd < 2; ++rnd) {
        if ((lr >> 3) == rnd) {
#pragma unroll
            for (int j = 0; j < 16; ++j) {
                *(v4u*)(slice + q * 1024 + (((j << 6) + (hi << 4)) ^ (q << 4))) =
                    *(v4u*)&acc[j];
            }
        }
        __asm__ volatile("s_waitcnt lgkmcnt(0)" ::: "memory");
#pragma unroll
        for (int q2 = 0; q2 < 8; ++q2) {
            v4u val = *(v4u*)(slice + q2 * 1024 + ((lane << 4) ^ (q2 << 4)));
            float* orow = out + (size_t)(rowbase + rnd * 8 + q2) * NKC;
            __builtin_nontemporal_store(val, (v4u*)(orow + (lane << 2)));
        }
        __asm__ volatile("s_waitcnt lgkmcnt(0)" ::: "memory");
    }
}

extern "C" void kernel_launch(void* const* d_in, const int* in_sizes, int n_in,
                              void* d_out, int out_size, void* d_ws, size_t ws_size,
                              hipStream_t stream) {
    const float* x        = (const float*)d_in[0];
    const float* clusters = (const float*)d_in[1];
    float* out = (float*)d_out;
    const int N = in_sizes[0] / ND;                 // 262144

    cluster_kernel<<<N / 64, 256, 0, stream>>>(x, clusters, out);
}